// Round 10
// baseline (1059.793 us; speedup 1.0000x reference)
//
#include <hip/hip_runtime.h>

// LSTM: SEQ=4096, BATCH=4096, IN=2, HID=8, fp32.
// R16 = within-wave ILP-2 on the R13/R15 verified structure.
// Each 16-lane slot carries TWO independent batch recurrences (bA, bA+1)
// with DPP-only communication (R8 tested ILP-2 but with ds_bpermute on the
// critical path -- that, not ILP-2, was its failure; R11 proved cross-wave
// TLP can't fill the ~130cy/step dependency bubbles; register-level ILP can).
//  - weights / biases / finalize constants: lane-functions, SHARED by both
//    chains (zero duplication).
//  - x: adjacent batches -> ONE float4 load feeds both chains (R8 trick).
//  - per chain, verbatim R15 step: 7-DPP gather tree, 8 pk_fma split-dots,
//    2 hadds, 2 exp2 + 2 rcp gates, raw-r0 gf exchange, packed finalize,
//    3 bank-masked ror8, all-lane c/h update, x-init+prefetch gap-fill.
//  - geometry: 512 blocks x 64 threads = 512 waves, 8 batches/wave.
//    Half the SIMDs idle BY DESIGN: kernel is latency-bound, only per-wave
//    cycles/step matter, and 2 chains/wave more than halve cycles/batch.
//  - PF=4 (prefetch distance ~4 steps ~ 1100cy, covers HBM latency;
//    float4 xb at PF=8 would cost 32 VGPRs for no benefit).
// Numerics identical to R6-R15: rows pre-scaled by -log2e (-2log2e for g~),
// c kept in scaled space c' = -2*log2e*c, sigmoid/tanh via exp2+rcp only.

#define SEQ   4096
#define BATCH 4096
#define PF    4

#define DPP_X1   0xB1  // quad_perm [1,0,3,2] : lane ^ 1
#define DPP_X2   0x4E  // quad_perm [2,3,0,1] : lane ^ 2
#define DPP_X3   0x1B  // quad_perm [3,2,1,0] : lane ^ 3
#define DPP_HMIR 0x141 // row_half_mirror     : lane ^ 7 (within 8-lane half)
#define DPP_ROR8 0x128 // row_ror:8           : lane ^ 8 (within 16-lane row)

typedef float v2f __attribute__((ext_vector_type(2)));

template<int CTRL>
__device__ __forceinline__ float rot(float v) {
    int i = __builtin_bit_cast(int, v);
    int r = __builtin_amdgcn_update_dpp(0, i, CTRL, 0xf, 0xf, true);
    return __builtin_bit_cast(float, r);
}
template<int CTRL>
__device__ __forceinline__ v2f dpp2(v2f v) {
    v2f r; r.x = rot<CTRL>(v.x); r.y = rot<CTRL>(v.y); return r;
}
// ror8 with bank-masked merge: lanes in enabled BANKS receive src[l^8],
// disabled banks keep 'oldv'. banks 0,1 = lanes 0-7 of each 16-lane row.
template<int BANKS>
__device__ __forceinline__ float ror8_keep(float oldv, float src) {
    int o = __builtin_bit_cast(int, oldv);
    int s = __builtin_bit_cast(int, src);
    int r = __builtin_amdgcn_update_dpp(o, s, DPP_ROR8, 0xf, BANKS, false);
    return __builtin_bit_cast(float, r);
}
__device__ __forceinline__ v2f vfma(v2f a, v2f b, v2f c) {
    return __builtin_elementwise_fma(a, b, c);
}

__global__ __launch_bounds__(64, 1) void lstm_kernel(
    const float* __restrict__ x,    // (SEQ, BATCH, 2)
    const float* __restrict__ h0,   // (1, BATCH, 8)
    const float* __restrict__ c0,   // (1, BATCH, 8)
    const float* __restrict__ Wih,  // (32, 2)
    const float* __restrict__ Whh,  // (32, 8)
    const float* __restrict__ bih,  // (32)
    const float* __restrict__ bhh,  // (32)
    float* __restrict__ out)        // (1, BATCH, 8)
{
    const int tid = threadIdx.x;
    const int l16 = tid & 15;
    const int u   = l16 & 7;         // unit 0..7
    const int hf  = l16 >> 3;        // 0: rows (i,g~)   1: rows (f,o)
    const int bA  = (blockIdx.x * 4 + (tid >> 4)) * 2;   // even; pair (bA,bA+1)

    const int row0 = hf * 8 + u;      // i-row (0..7)  or f-row (8..15)
    const int row1 = 16 + row0;       // g~-row (16..23) or o-row (24..31)

    const float L2E = 1.4426950408889634f;
    const float n2L = -2.0f * L2E;
    // pre-activation scales folded into weights:
    //   sigmoid rows (i,f,o): -L2E     tanh row (g~): -2*L2E
    const float smul0 = -L2E;
    const float smul1 = hf ? -L2E : n2L;
    // packed finalize: act = pk_fma((r0,r1), {n2L,2}, {0,addc})
    //   hf0: act.x = gi (-2L2E*sigma_i), act.y = gg (tanh)
    //   hf1: act.x unused (gf exchanged RAW), act.y = go2 (2*sigma_o)
    const v2f actm = { n2L, 2.0f };
    const v2f acta = { 0.0f, hf ? 0.0f : -1.0f };

    // weights paired for split-dot: pair m covers columns (u^m, u^m^7)
    const float* wr0 = Whh + row0 * 8;
    const float* wr1 = Whh + row1 * 8;
    v2f W0[4], W1[4];
#pragma unroll
    for (int m = 0; m < 4; ++m) {
        const int ka = u ^ m, kb = ka ^ 7;
        W0[m] = (v2f){ wr0[ka], wr0[kb] } * smul0;
        W1[m] = (v2f){ wr1[ka], wr1[kb] } * smul1;
    }
    const v2f WX0 = (v2f){ Wih[2 * row0], Wih[2 * row0 + 1] } * smul0;
    const v2f WX1 = (v2f){ Wih[2 * row1], Wih[2 * row1 + 1] } * smul1;
    const v2f B0  = { (bih[row0] + bhh[row0]) * smul0, 0.0f };
    const v2f B1  = { (bih[row1] + bhh[row1]) * smul1, 0.0f };

    // two independent recurrences (c in scaled space; valid in ALL lanes)
    float cA = c0[bA * 8 + u]     * n2L, hA = h0[bA * 8 + u];
    float cB = c0[bA * 8 + 8 + u] * n2L, hB = h0[bA * 8 + 8 + u];

    // x as float4 rows of BATCH/2: one load feeds both chains
    const float4* __restrict__ xp4 = (const float4*)x;
    const int xcol = bA >> 1;
    float4 xb[PF];
#pragma unroll
    for (int p = 0; p < PF; ++p) xb[p] = xp4[p * (BATCH / 2) + xcol];

    // carried next-step init accumulators (h-independent x-part of the dot)
    v2f a0nA, a1nA, a0nB, a1nB;
    {
        const v2f xvA = { xb[0].x, xb[0].y };
        const v2f xvB = { xb[0].z, xb[0].w };
        a0nA = vfma(xvA, WX0, B0);  a1nA = vfma(xvA, WX1, B1);
        a0nB = vfma(xvB, WX0, B0);  a1nB = vfma(xvB, WX1, B1);
    }

    for (int s = 0; s < SEQ; s += PF) {
#pragma unroll
        for (int p = 0; p < PF; ++p) {
            v2f a0A = a0nA, a1A = a1nA;   // inits precomputed in trans gaps
            v2f a0B = a0nB, a1B = a1nB;

            // ---- h-gather trees, both chains (independent DPP chains)
            v2f P0A; P0A.x = hA; P0A.y = rot<DPP_HMIR>(hA);
            v2f P0B; P0B.x = hB; P0B.y = rot<DPP_HMIR>(hB);
            const v2f P1A = dpp2<DPP_X1>(P0A);
            const v2f P1B = dpp2<DPP_X1>(P0B);
            const v2f P2A = dpp2<DPP_X2>(P0A);
            const v2f P2B = dpp2<DPP_X2>(P0B);
            const v2f P3A = dpp2<DPP_X3>(P0A);
            const v2f P3B = dpp2<DPP_X3>(P0B);

            // ---- packed split-dots, interleaved A/B
            a0A = vfma(P0A, W0[0], a0A);  a1A = vfma(P0A, W1[0], a1A);
            a0B = vfma(P0B, W0[0], a0B);  a1B = vfma(P0B, W1[0], a1B);
            a0A = vfma(P1A, W0[1], a0A);  a1A = vfma(P1A, W1[1], a1A);
            a0B = vfma(P1B, W0[1], a0B);  a1B = vfma(P1B, W1[1], a1B);
            a0A = vfma(P2A, W0[2], a0A);  a1A = vfma(P2A, W1[2], a1A);
            a0B = vfma(P2B, W0[2], a0B);  a1B = vfma(P2B, W1[2], a1B);
            a0A = vfma(P3A, W0[3], a0A);  a1A = vfma(P3A, W1[3], a1A);
            a0B = vfma(P3B, W0[3], a0B);  a1B = vfma(P3B, W1[3], a1B);
            const float pre0A = a0A.x + a0A.y;         // already scaled
            const float pre1A = a1A.x + a1A.y;
            const float pre0B = a0B.x + a0B.y;
            const float pre1B = a1B.x + a1B.y;

            // ---- gate activations (4 independent exp2, then 4 rcp)
            const float e0A = __builtin_amdgcn_exp2f(pre0A);
            const float e1A = __builtin_amdgcn_exp2f(pre1A);
            const float e0B = __builtin_amdgcn_exp2f(pre0B);
            const float e1B = __builtin_amdgcn_exp2f(pre1B);

            // [gap-fill: x prefetch for slot p, independent of everything]
            const int sn = (s + p + PF) & (SEQ - 1);   // uniform wrap
            xb[p] = xp4[sn * (BATCH / 2) + xcol];

            const float r0A = __builtin_amdgcn_rcpf(e0A + 1.0f);
            const float r1A = __builtin_amdgcn_rcpf(e1A + 1.0f);
            const float r0B = __builtin_amdgcn_rcpf(e0B + 1.0f);
            const float r1B = __builtin_amdgcn_rcpf(e1B + 1.0f);

            // ---- gf from RAW r0; packed finalize; 3 ror8 per chain
            const float gfA = ror8_keep<0x3>(r0A, r0A);   // all: sigma_f
            const float gfB = ror8_keep<0x3>(r0B, r0B);
            v2f rrA; rrA.x = r0A; rrA.y = r1A;
            v2f rrB; rrB.x = r0B; rrB.y = r1B;
            const v2f actA = vfma(rrA, actm, acta);       // (gi|-, gg|go2)
            const v2f actB = vfma(rrB, actm, acta);
            const float go2A = ror8_keep<0x3>(actA.y, actA.y); // all: 2sig_o
            const float go2B = ror8_keep<0x3>(actB.y, actB.y);
            const float ppA  = actA.x * actA.y;           // hf0: gi*gg
            const float ppB  = actB.x * actB.y;
            const float igA  = ror8_keep<0xC>(ppA, ppA);  // all: gi*gg
            const float igB  = ror8_keep<0xC>(ppB, ppB);

            // ---- c/h updates (all lanes; h replicated by construction)
            cA = __builtin_fmaf(gfA, cA, igA);
            cB = __builtin_fmaf(gfB, cB, igB);
            const float e2A = __builtin_amdgcn_exp2f(cA);
            const float e2B = __builtin_amdgcn_exp2f(cB);

            // [gap-fill in the c-exp2 shadow: next-step x-inits + ngo]
            const float4 xcn = xb[(p + 1) & (PF - 1)];
            const v2f xvnA = { xcn.x, xcn.y };
            const v2f xvnB = { xcn.z, xcn.w };
            a0nA = vfma(xvnA, WX0, B0);  a1nA = vfma(xvnA, WX1, B1);
            a0nB = vfma(xvnB, WX0, B0);  a1nB = vfma(xvnB, WX1, B1);
            const float ngoA = go2A * -0.5f;
            const float ngoB = go2B * -0.5f;

            const float r2A = __builtin_amdgcn_rcpf(e2A + 1.0f);
            const float r2B = __builtin_amdgcn_rcpf(e2B + 1.0f);
            hA = __builtin_fmaf(go2A, r2A, ngoA);      // h = 2sig*r - sig
            hB = __builtin_fmaf(go2B, r2B, ngoB);
        }
    }

    if (!hf) {
        out[bA * 8 + u]     = hA;
        out[bA * 8 + 8 + u] = hB;
    }
}

extern "C" void kernel_launch(void* const* d_in, const int* in_sizes, int n_in,
                              void* d_out, int out_size, void* d_ws, size_t ws_size,
                              hipStream_t stream) {
    const float* x   = (const float*)d_in[0];
    const float* h0  = (const float*)d_in[1];
    const float* c0  = (const float*)d_in[2];
    const float* Wih = (const float*)d_in[3];
    const float* Whh = (const float*)d_in[4];
    const float* bih = (const float*)d_in[5];
    const float* bhh = (const float*)d_in[6];
    float* out = (float*)d_out;

    dim3 grid(BATCH / 8);    // 512 single-wave blocks (2/CU, 2 SIMDs/CU busy)
    dim3 block(64);          // 1 wave = 4 slots x 16 lanes x 2 chains = 8 batches
    hipLaunchKernelGGL(lstm_kernel, grid, block, 0, stream,
                       x, h0, c0, Wih, Whh, bih, bhh, out);
}

// Round 11
// 655.850 us; speedup vs baseline: 1.6159x; 1.6159x over previous
//
#include <hip/hip_runtime.h>

// LSTM: SEQ=4096, BATCH=4096, IN=2, HID=8, fp32.
// R17 = FINAL: revert to R13, the session's best verified kernel
// (533-546us counter, vs 827 baseline). R14-R16 established the floor:
//  - TLP exhausted (R7/R11: cross-wave issue serializes, 2x issue > wall)
//  - in-wave ILP exhausted (R16: chain-B marginal issue ~100%, stall unchanged)
//  - trans-trim exhausted (R14: path lengthens as issue shrinks)
//  - micro-packing neutral (R15)
// Structure: wall ~320 cy/step = ~190 issue (6 trans @ ~16cy + ~47 VALU/DPP
// @ 2cy) + ~130 structural stall no parallelism form can fill. The floor op
// is 5 transcendental activations per serial batch-step on the trans pipe.
//
// Kernel: 16 lanes/batch (l16 = hf*8+u; hf0 owns gate rows (i,g~) of unit
// u, hf1 owns (f,o)); packed split-dots P_m=(h_{u^m},h_{u^m^7}) via 7-DPP
// tree + 8 v_pk_fma_f32 + 2 hadds; 2 exp2 + 2 rcp gate activations;
// 3 bank-masked ror8 exchanges {gf, go2, i*g~}; all-lane c/h update (h
// replicated by construction); x-init + x-prefetch + ngo gap-filled into
// the exp2/rcp latency shadows; grid 256 x block 256 = 1024 waves =
// 1 wave/SIMD on all 256 CUs (the unique full-chip minimal-issue geometry).
// Numerics: rows pre-scaled by -log2e (-2log2e for g~), c kept in scaled
// space c' = -2*log2e*c, sigmoid/tanh via exp2+rcp only.

#define SEQ   4096
#define BATCH 4096
#define PF    8

#define DPP_X1   0xB1  // quad_perm [1,0,3,2] : lane ^ 1
#define DPP_X2   0x4E  // quad_perm [2,3,0,1] : lane ^ 2
#define DPP_X3   0x1B  // quad_perm [3,2,1,0] : lane ^ 3
#define DPP_HMIR 0x141 // row_half_mirror     : lane ^ 7 (within 8-lane half)
#define DPP_ROR8 0x128 // row_ror:8           : lane ^ 8 (within 16-lane row)

typedef float v2f __attribute__((ext_vector_type(2)));

template<int CTRL>
__device__ __forceinline__ float rot(float v) {
    int i = __builtin_bit_cast(int, v);
    int r = __builtin_amdgcn_update_dpp(0, i, CTRL, 0xf, 0xf, true);
    return __builtin_bit_cast(float, r);
}
template<int CTRL>
__device__ __forceinline__ v2f dpp2(v2f v) {
    v2f r; r.x = rot<CTRL>(v.x); r.y = rot<CTRL>(v.y); return r;
}
// ror8 with bank-masked merge: lanes in enabled BANKS receive src[l^8],
// disabled banks keep 'oldv'. banks 0,1 = lanes 0-7 of each 16-lane row.
template<int BANKS>
__device__ __forceinline__ float ror8_keep(float oldv, float src) {
    int o = __builtin_bit_cast(int, oldv);
    int s = __builtin_bit_cast(int, src);
    int r = __builtin_amdgcn_update_dpp(o, s, DPP_ROR8, 0xf, BANKS, false);
    return __builtin_bit_cast(float, r);
}
__device__ __forceinline__ v2f vfma(v2f a, v2f b, v2f c) {
    return __builtin_elementwise_fma(a, b, c);
}

__global__ __launch_bounds__(256, 1) void lstm_kernel(
    const float* __restrict__ x,    // (SEQ, BATCH, 2)
    const float* __restrict__ h0,   // (1, BATCH, 8)
    const float* __restrict__ c0,   // (1, BATCH, 8)
    const float* __restrict__ Wih,  // (32, 2)
    const float* __restrict__ Whh,  // (32, 8)
    const float* __restrict__ bih,  // (32)
    const float* __restrict__ bhh,  // (32)
    float* __restrict__ out)        // (1, BATCH, 8)
{
    const int tid = threadIdx.x;
    const int l16 = tid & 15;
    const int u   = l16 & 7;         // unit 0..7
    const int hf  = l16 >> 3;        // 0: rows (i,g~)   1: rows (f,o)
    const int b   = blockIdx.x * 16 + (tid >> 4);

    const int row0 = hf * 8 + u;      // i-row (0..7)  or f-row (8..15)
    const int row1 = 16 + row0;       // g~-row (16..23) or o-row (24..31)

    const float L2E = 1.4426950408889634f;
    const float n2L = -2.0f * L2E;
    // pre-activation scales folded into weights:
    //   sigmoid rows (i,f,o): -L2E     tanh row (g~): -2*L2E
    const float smul0 = -L2E;
    const float smul1 = hf ? -L2E : n2L;
    // act0 = r0*tm0:        i -> -2L2E*sigma (scaled-c form)   f -> sigma
    // act1 = r1*2 + addc1:  g~ -> tanh                         o -> 2*sigma
    const float tm0   = hf ? 1.0f : n2L;
    const float addc1 = hf ? 0.0f : -1.0f;

    // weights paired for split-dot: pair m covers columns (u^m, u^m^7)
    const float* wr0 = Whh + row0 * 8;
    const float* wr1 = Whh + row1 * 8;
    v2f W0[4], W1[4];
#pragma unroll
    for (int m = 0; m < 4; ++m) {
        const int ka = u ^ m, kb = ka ^ 7;
        W0[m] = (v2f){ wr0[ka], wr0[kb] } * smul0;
        W1[m] = (v2f){ wr1[ka], wr1[kb] } * smul1;
    }
    const v2f WX0 = (v2f){ Wih[2 * row0], Wih[2 * row0 + 1] } * smul0;
    const v2f WX1 = (v2f){ Wih[2 * row1], Wih[2 * row1 + 1] } * smul1;
    const v2f B0  = { (bih[row0] + bhh[row0]) * smul0, 0.0f };
    const v2f B1  = { (bih[row1] + bhh[row1]) * smul1, 0.0f };

    // state: c in scaled space c' = -2*L2E*c; valid in ALL lanes (no mask)
    float c = c0[b * 8 + u] * n2L;
    float h = h0[b * 8 + u];

    const float2* __restrict__ xp2 = (const float2*)x;
    float2 xb[PF];
#pragma unroll
    for (int p = 0; p < PF; ++p) xb[p] = xp2[p * BATCH + b];

    // carried next-step init accumulators (h-independent x-part of the dot)
    v2f a0n, a1n;
    {
        const v2f xv0 = { xb[0].x, xb[0].y };
        a0n = vfma(xv0, WX0, B0);
        a1n = vfma(xv0, WX1, B1);
    }

    for (int s = 0; s < SEQ; s += PF) {
#pragma unroll
        for (int p = 0; p < PF; ++p) {
            v2f a0 = a0n, a1 = a1n;   // init was precomputed in a trans gap

            // ---- h-gather: P_m = (h_{u^m}, h_{u^m^7}); 7 DPPs total
            v2f P0; P0.x = h; P0.y = rot<DPP_HMIR>(h);
            const v2f P1 = dpp2<DPP_X1>(P0);
            const v2f P2 = dpp2<DPP_X2>(P0);
            const v2f P3 = dpp2<DPP_X3>(P0);

            // ---- two packed split-dots (one per owned row)
            a0 = vfma(P0, W0[0], a0);  a1 = vfma(P0, W1[0], a1);
            a0 = vfma(P1, W0[1], a0);  a1 = vfma(P1, W1[1], a1);
            a0 = vfma(P2, W0[2], a0);  a1 = vfma(P2, W1[2], a1);
            a0 = vfma(P3, W0[3], a0);  a1 = vfma(P3, W1[3], a1);
            const float pre0 = a0.x + a0.y;            // already scaled
            const float pre1 = a1.x + a1.y;

            // ---- gate activations
            const float e0 = __builtin_amdgcn_exp2f(pre0);
            const float e1 = __builtin_amdgcn_exp2f(pre1);

            // [gap-fill: x prefetch for slot p, independent of everything]
            const int sn = (s + p + PF) & (SEQ - 1);   // uniform wrap
            xb[p] = xp2[sn * BATCH + b];

            const float r0 = __builtin_amdgcn_rcpf(e0 + 1.0f);
            const float r1 = __builtin_amdgcn_rcpf(e1 + 1.0f);
            const float act0 = r0 * tm0;                        // gi | gf
            const float act1 = __builtin_fmaf(r1, 2.0f, addc1); // gg | go2

            // ---- local product + 3 bank-masked ror8 exchanges (all-lane)
            const float pp  = act0 * act1;                // hf0: gi*gg
            const float gf  = ror8_keep<0x3>(act0, act0); // all: sigma_f
            const float go2 = ror8_keep<0x3>(act1, act1); // all: 2*sigma_o
            const float ig  = ror8_keep<0xC>(pp, pp);     // all: gi*gg

            // ---- c/h update in ALL lanes (h replicated by construction)
            c = __builtin_fmaf(gf, c, ig);             // scaled-c recurrence
            const float e2 = __builtin_amdgcn_exp2f(c);

            // [gap-fill inside the c-exp2 shadow: next-step x-init + ngo]
            const float2 xcn = xb[(p + 1) & (PF - 1)];
            const v2f xvn = { xcn.x, xcn.y };
            a0n = vfma(xvn, WX0, B0);
            a1n = vfma(xvn, WX1, B1);
            const float ngo = go2 * -0.5f;

            const float r2 = __builtin_amdgcn_rcpf(e2 + 1.0f);
            h = __builtin_fmaf(go2, r2, ngo);          // h = 2sig*r - sig
        }
    }

    if (!hf) out[b * 8 + u] = h;
}

extern "C" void kernel_launch(void* const* d_in, const int* in_sizes, int n_in,
                              void* d_out, int out_size, void* d_ws, size_t ws_size,
                              hipStream_t stream) {
    const float* x   = (const float*)d_in[0];
    const float* h0  = (const float*)d_in[1];
    const float* c0  = (const float*)d_in[2];
    const float* Wih = (const float*)d_in[3];
    const float* Whh = (const float*)d_in[4];
    const float* bih = (const float*)d_in[5];
    const float* bhh = (const float*)d_in[6];
    float* out = (float*)d_out;

    dim3 grid(BATCH / 16);   // 256 blocks -> 1 block/CU on all 256 CUs
    dim3 block(256);         // 4 waves/block -> 1 wave/SIMD (full chip)
    hipLaunchKernelGGL(lstm_kernel, grid, block, 0, stream,
                       x, h0, c0, Wih, Whh, bih, bhh, out);
}